// Round 12
// baseline (63.713 us; speedup 1.0000x reference)
//
#include <hip/hip_runtime.h>
#include <math.h>

#define BATCH   64
#define IN_DIM  8192
#define OUT_DIM 2048
#define BRANCH  4
#define CHUNK   2048
#define KT      128    // k per LDS tile
#define NTSEG   8      // tiles per K-half (1024 / KT)

typedef __attribute__((ext_vector_type(8))) short short8;   // 8 x bf16 (4 VGPR) MFMA operand
typedef __attribute__((ext_vector_type(4))) short short4v;  // 8-byte packed bf16x4
typedef __attribute__((ext_vector_type(4))) float f32x4;

__device__ __forceinline__ float sigmoidf_(float x) {
    return 1.0f / (1.0f + expf(-x));
}

// round-to-nearest-even fp32 -> bf16 bit pattern (low 16 bits of result)
__device__ __forceinline__ unsigned rne_bf16(float f) {
    unsigned u = __float_as_uint(f);
    return (u + 0x7fffu + ((u >> 16) & 1u)) >> 16;
}

// Barrier that does NOT drain vmcnt: LDS-visibility only (R7-verified safe).
#define LBAR()                                                   \
    do {                                                         \
        asm volatile("s_waitcnt lgkmcnt(0)" ::: "memory");       \
        __builtin_amdgcn_s_barrier();                            \
        asm volatile("" ::: "memory");                           \
    } while (0)

// agent-scope (device) coherent accessors for cross-XCD partials
__device__ __forceinline__ void pstore(float* p, float v) {
    __hip_atomic_store(p, v, __ATOMIC_RELAXED, __HIP_MEMORY_SCOPE_AGENT);
}
__device__ __forceinline__ float pload(const float* p) {
    return __hip_atomic_load(p, __ATOMIC_RELAXED, __HIP_MEMORY_SCOPE_AGENT);
}

// ---------------------------------------------------------------------------
// prep: X fp32 [64][8192] -> A-fragment-layout bf16 hi/lo streams (verified R2-R10).
// Also clears the 128 pairing flags (kernel boundary makes stores visible).
__global__ __launch_bounds__(256) void prep_x(const float* __restrict__ X,
                                              short8* __restrict__ Xfh,
                                              short8* __restrict__ Xfl,
                                              int* __restrict__ flags) {
    const int gid = blockIdx.x * 256 + threadIdx.x;   // 65536 frag-lanes
    if (gid < 128) flags[gid] = 0;
    const int l  = gid & 63;
    const int kk = (gid >> 6) & 63;
    const int s  = (gid >> 12) & 3;
    const int j  = gid >> 14;
    const int n  = s * 16 + (l & 15);
    const int k0 = kk * 32 + ((l >> 4) << 3);
    const float* p = X + (size_t)n * IN_DIM + j * CHUNK + k0;
    const f32x4 a = *(const f32x4*)p;
    const f32x4 c = *(const f32x4*)(p + 4);
    float v[8] = {a[0], a[1], a[2], a[3], c[0], c[1], c[2], c[3]};
    short8 h, lo;
#pragma unroll
    for (int e = 0; e < 8; ++e) {
        unsigned hb = rne_bf16(v[e]);
        float fh = __uint_as_float(hb << 16);
        unsigned lb = rne_bf16(v[e] - fh);
        h[e]  = (short)hb;
        lo[e] = (short)lb;
    }
    Xfh[gid] = h;
    Xfl[gid] = lo;
}

// ---------------------------------------------------------------------------
// stage fp32 W regs -> split bf16 hi/lo in swizzled LDS (verified R10).
// 64 rows x 256B; swizzle key = ((row>>2)&15)<<4  (== o_l<<4 on the read side).
__device__ __forceinline__ void stage_store(char* Wh, char* Wl, const f32x4* wr,
                                            int wbyte0, int swz, int kq) {
#pragma unroll
    for (int i = 0; i < 4; ++i) {
        unsigned hb[4], lb[4];
#pragma unroll
        for (int e = 0; e < 4; ++e) {
            float f = wr[i][e];
            unsigned h = rne_bf16(f);
            float fh = __uint_as_float(h << 16);
            unsigned l = rne_bf16(f - fh);
            hb[e] = h; lb[e] = l;
        }
        short4v vh = { (short)hb[0], (short)hb[1], (short)hb[2], (short)hb[3] };
        short4v vl = { (short)lb[0], (short)lb[1], (short)lb[2], (short)lb[3] };
        const int kb   = (kq << 5) + (i << 3);
        const int byte = wbyte0 + (kb ^ swz);
        *(short4v*)(Wh + byte) = vh;
        *(short4v*)(Wl + byte) = vl;
    }
}

// ---------------------------------------------------------------------------
// Fused block-diagonal GEMM + dendritic decay + LIF + spike, K-split paired.
// grid: 256 = 128 o-tiles x 2 K-halves. block: 512 thr = 8 waves (nhalf x branch).
// kseg1 blocks publish partials (agent atomics + release flag);
// kseg0 blocks spin (acquire), reduce deterministically, run LIF, write out.
__global__ __launch_bounds__(512) void dend_fused(
    const short8* __restrict__ Xfh,
    const short8* __restrict__ Xfl,
    const float*  __restrict__ W,
    const float*  __restrict__ mem,
    const float*  __restrict__ spike,
    const float*  __restrict__ d_input,
    const float*  __restrict__ v_th,
    const float*  __restrict__ bias,
    const float*  __restrict__ tau_m,
    const float*  __restrict__ tau_n,
    float* __restrict__ P,
    int*   __restrict__ flags,
    float* __restrict__ out)
{
    __shared__ __align__(16) char WhL[2][64 * 256];   // 16 KB per buffer
    __shared__ __align__(16) char WlL[2][64 * 256];

    const int t    = threadIdx.x;
    const int bid  = blockIdx.x;
    const int ot   = bid >> 1;         // o-tile: outputs ot*16 .. +16
    const int kseg = bid & 1;          // K-half
    const int lane = t & 63;
    const int wv   = t >> 6;           // 0..7
    const int nsp  = wv >> 2;          // n-half
    const int j    = wv & 3;           // branch

    // W staging: 8 threads per local row (64 rows), 16 fp32 each.
    const int ri  = t >> 3;            // 0..63
    const int kq  = t & 7;
    const float* wsrc = W + (size_t)(ot * 64 + ri) * IN_DIM
                          + (ri & 3) * CHUNK + kseg * 1024 + kq * 16;
    const int wbyte0 = ri << 8;
    const int swz    = ((ri >> 2) & 15) << 4;

    // B-frag read addressing: local row lr = o_l*4 + j ; key (lr>>2)&15 == o_l.
    const int o_l  = lane & 15;
    const int q    = lane >> 4;        // 0..3
    const int brow = (o_l * 4 + j) << 8;
    const int bswz = o_l << 4;
    const int kgrp = q << 4;

    // A-frag streams for strips s0 = nsp*2, s0+1; kk_local 0..31 (+kseg*32)
    const int s0 = nsp * 2;
    const short8* pAh0 = Xfh + (j * 4 + s0) * 4096 + kseg * 2048 + lane;
    const short8* pAl0 = Xfl + (j * 4 + s0) * 4096 + kseg * 2048 + lane;
    const short8* pAh1 = pAh0 + 4096;
    const short8* pAl1 = pAl0 + 4096;

    f32x4 acc0 = {0.f, 0.f, 0.f, 0.f};   // strip s0
    f32x4 acc1 = {0.f, 0.f, 0.f, 0.f};   // strip s0+1

    f32x4  wr[4];
    short8 AXh0[2], AXl0[2], AXh1[2], AXl1[2];
    short8 AYh0[2], AYl0[2], AYh1[2], AYl1[2];

#define LOADA(Pn, base)                                        \
  if ((base) < 32) {                                           \
    _Pragma("unroll")                                          \
    for (int u = 0; u < 2; ++u) {                              \
        A##Pn##h0[u] = pAh0[((base) + u) * 64];                \
        A##Pn##l0[u] = pAl0[((base) + u) * 64];                \
        A##Pn##h1[u] = pAh1[((base) + u) * 64];                \
        A##Pn##l1[u] = pAl1[((base) + u) * 64];                \
    }                                                          \
  }

#define CONSUME(Pn, kt, stbase)                                                        \
  { _Pragma("unroll")                                                                  \
    for (int u = 0; u < 2; ++u) {                                                      \
        const int off = ((((stbase) + u) << 6) + kgrp) ^ bswz;                         \
        const short8 bh = *(const short8*)(&WhL[(kt) & 1][brow + off]);                \
        const short8 bl = *(const short8*)(&WlL[(kt) & 1][brow + off]);                \
        acc0 = __builtin_amdgcn_mfma_f32_16x16x32_bf16(A##Pn##h0[u], bh, acc0, 0,0,0); \
        acc1 = __builtin_amdgcn_mfma_f32_16x16x32_bf16(A##Pn##h1[u], bh, acc1, 0,0,0); \
        acc0 = __builtin_amdgcn_mfma_f32_16x16x32_bf16(A##Pn##l0[u], bh, acc0, 0,0,0); \
        acc1 = __builtin_amdgcn_mfma_f32_16x16x32_bf16(A##Pn##l1[u], bh, acc1, 0,0,0); \
        acc0 = __builtin_amdgcn_mfma_f32_16x16x32_bf16(A##Pn##h0[u], bl, acc0, 0,0,0); \
        acc1 = __builtin_amdgcn_mfma_f32_16x16x32_bf16(A##Pn##h1[u], bl, acc1, 0,0,0); \
    } }

    // ---- prologue: W tiles 0,1 ; A kk 0,1 ----
#pragma unroll
    for (int i = 0; i < 4; ++i)
        wr[i] = *(const f32x4*)(wsrc + i * 4);
    stage_store(&WhL[0][0], &WlL[0][0], wr, wbyte0, swz, kq);
#pragma unroll
    for (int i = 0; i < 4; ++i)
        wr[i] = *(const f32x4*)(wsrc + KT + i * 4);
    LOADA(X, 0)
    LBAR();

#pragma unroll 1
    for (int kt = 0; kt < NTSEG; ++kt) {
        if (kt + 1 < NTSEG)
            stage_store(&WhL[(kt + 1) & 1][0], &WlL[(kt + 1) & 1][0],
                        wr, wbyte0, swz, kq);
        if (kt + 2 < NTSEG) {
#pragma unroll
            for (int i = 0; i < 4; ++i)
                wr[i] = *(const f32x4*)(wsrc + (kt + 2) * KT + i * 4);
        }
        LOADA(Y, kt * 4 + 2)
        CONSUME(X, kt, 0)
        LOADA(X, kt * 4 + 4)
        CONSUME(Y, kt, 2)
        LBAR();
    }
#undef LOADA
#undef CONSUME

    // ---- in-block partial: acc -> Ysum LDS (alias onto dead W buffers) ----
    float* Ysum = (float*)&WhL[0][0];          // [4 j][64 n][17] = 17.4 KB
    {
#pragma unroll
        for (int r = 0; r < 4; ++r) {
            const int n0 = s0 * 16 + q * 4 + r;
            Ysum[(j * 64 + n0)      * 17 + o_l] = acc0[r];
            Ysum[(j * 64 + n0 + 16) * 17 + o_l] = acc1[r];
        }
    }
    __syncthreads();

    const int fbase = ot * 4096;               // P slot: [4 j][64 n][16 oo]

    if (kseg == 1) {
        // publish partial via agent-scope stores, then release flag
#pragma unroll
        for (int p = 0; p < 8; ++p) {
            const int e  = t + (p << 9);       // 0..4095
            const int j2 = e >> 10;
            const int n  = (e >> 4) & 63;
            const int oo = e & 15;
            pstore(&P[fbase + e], Ysum[(j2 * 64 + n) * 17 + oo]);
        }
        __syncthreads();
        __threadfence();
        if (t == 0)
            __hip_atomic_store(&flags[ot], 1, __ATOMIC_RELEASE,
                               __HIP_MEMORY_SCOPE_AGENT);
    } else {
        // prefetch LIF inputs (independent of partner) before the spin
        float4 tn4[2], bb4[2], di4[2];
        float  al[2], vt[2], mm[2], sp[2];
        int    idxv[2];
#pragma unroll
        for (int p = 0; p < 2; ++p) {
            const int e  = t + (p << 9);       // 0..1023 = 64 n x 16 oo
            const int oo = e & 15;
            const int n  = e >> 4;
            const int og = ot * 16 + oo;
            const int idx = n * OUT_DIM + og;
            idxv[p] = idx;
            tn4[p] = ((const float4*)tau_n)[og];
            bb4[p] = ((const float4*)bias)[og];
            di4[p] = ((const float4*)d_input)[idx];
            al[p]  = sigmoidf_(tau_m[og]);
            vt[p]  = v_th[idx];
            mm[p]  = mem[idx];
            sp[p]  = spike[idx];
        }
        if (t == 0) {
            while (__hip_atomic_load(&flags[ot], __ATOMIC_ACQUIRE,
                                     __HIP_MEMORY_SCOPE_AGENT) == 0) {
                __builtin_amdgcn_s_sleep(4);
            }
        }
        __syncthreads();

#pragma unroll
        for (int p = 0; p < 2; ++p) {
            const int e  = t + (p << 9);
            const int oo = e & 15;
            const int n  = e >> 4;
            const int idx = idxv[p];

            const float y0 = Ysum[(0 * 64 + n) * 17 + oo] + pload(&P[fbase + 0 * 1024 + n * 16 + oo]);
            const float y1 = Ysum[(1 * 64 + n) * 17 + oo] + pload(&P[fbase + 1 * 1024 + n * 16 + oo]);
            const float y2 = Ysum[(2 * 64 + n) * 17 + oo] + pload(&P[fbase + 2 * 1024 + n * 16 + oo]);
            const float y3 = Ysum[(3 * 64 + n) * 17 + oo] + pload(&P[fbase + 3 * 1024 + n * 16 + oo]);

            float l = 0.0f;
            { const float bt = sigmoidf_(tn4[p].x); l += bt * di4[p].x + (1.0f - bt) * (y0 + bb4[p].x); }
            { const float bt = sigmoidf_(tn4[p].y); l += bt * di4[p].y + (1.0f - bt) * (y1 + bb4[p].y); }
            { const float bt = sigmoidf_(tn4[p].z); l += bt * di4[p].z + (1.0f - bt) * (y2 + bb4[p].z); }
            { const float bt = sigmoidf_(tn4[p].w); l += bt * di4[p].w + (1.0f - bt) * (y3 + bb4[p].w); }

            const float m = mm[p] * al[p] + (1.0f - al[p]) * l - vt[p] * sp[p];
            out[idx] = m;
            out[BATCH * OUT_DIM + idx] = (m - vt[p]) > 0.0f ? 1.0f : 0.0f;
        }
    }
}

extern "C" void kernel_launch(void* const* d_in, const int* in_sizes, int n_in,
                              void* d_out, int out_size, void* d_ws, size_t ws_size,
                              hipStream_t stream) {
    const float* X     = (const float*)d_in[0];
    const float* mem   = (const float*)d_in[1];
    const float* spike = (const float*)d_in[2];
    const float* dinp  = (const float*)d_in[3];
    const float* vth   = (const float*)d_in[4];
    const float* W     = (const float*)d_in[5];
    const float* b     = (const float*)d_in[6];
    const float* tm    = (const float*)d_in[7];
    const float* tn    = (const float*)d_in[8];
    float* out = (float*)d_out;

    // workspace: Xfh (1 MB) | Xfl (1 MB) | P (2 MB) | flags (512 B)
    short8* Xfh   = (short8*)d_ws;
    short8* Xfl   = (short8*)((char*)d_ws + (1u << 20));
    float*  P     = (float*)((char*)d_ws + (2u << 20));
    int*    flags = (int*)((char*)d_ws + (4u << 20));

    prep_x<<<256, 256, 0, stream>>>(X, Xfh, Xfl, flags);
    dend_fused<<<256, 512, 0, stream>>>(Xfh, Xfl, W, mem, spike, dinp, vth,
                                        b, tm, tn, P, flags, out);
}

// Round 13
// 32.637 us; speedup vs baseline: 1.9522x; 1.9522x over previous
//
#include <hip/hip_runtime.h>
#include <math.h>

#define BATCH   64
#define IN_DIM  8192
#define OUT_DIM 2048
#define BRANCH  4
#define CHUNK   2048
#define NSEG    2      // K-split across blocks
#define KSEG    1024   // CHUNK / NSEG
#define KT      128    // k per LDS tile
#define NT      8      // KSEG / KT

typedef __attribute__((ext_vector_type(8))) short short8;   // 8 x bf16 (4 VGPR) MFMA operand
typedef __attribute__((ext_vector_type(4))) short short4v;  // 8-byte packed bf16x4
typedef __attribute__((ext_vector_type(4))) float f32x4;

__device__ __forceinline__ float sigmoidf_(float x) {
    return 1.0f / (1.0f + expf(-x));
}

// round-to-nearest-even fp32 -> bf16 bit pattern (low 16 bits of result)
__device__ __forceinline__ unsigned rne_bf16(float f) {
    unsigned u = __float_as_uint(f);
    return (u + 0x7fffu + ((u >> 16) & 1u)) >> 16;
}

// Barrier that does NOT drain vmcnt: LDS-visibility only (R7-verified safe).
#define LBAR()                                                   \
    do {                                                         \
        asm volatile("s_waitcnt lgkmcnt(0)" ::: "memory");       \
        __builtin_amdgcn_s_barrier();                            \
        asm volatile("" ::: "memory");                           \
    } while (0)

// ---------------------------------------------------------------------------
// prep: X fp32 [64][8192] -> A-fragment-layout bf16 hi/lo streams.
__global__ __launch_bounds__(256) void prep_x(const float* __restrict__ X,
                                              short8* __restrict__ Xfh,
                                              short8* __restrict__ Xfl) {
    const int gid = blockIdx.x * 256 + threadIdx.x;   // 65536 frag-lanes
    const int l  = gid & 63;
    const int kk = (gid >> 6) & 63;
    const int s  = (gid >> 12) & 3;
    const int j  = gid >> 14;
    const int n  = s * 16 + (l & 15);
    const int k0 = kk * 32 + ((l >> 4) << 3);
    const float* p = X + (size_t)n * IN_DIM + j * CHUNK + k0;
    const f32x4 a = *(const f32x4*)p;
    const f32x4 c = *(const f32x4*)(p + 4);
    float v[8] = {a[0], a[1], a[2], a[3], c[0], c[1], c[2], c[3]};
    short8 h, lo;
#pragma unroll
    for (int e = 0; e < 8; ++e) {
        unsigned hb = rne_bf16(v[e]);
        float fh = __uint_as_float(hb << 16);
        unsigned lb = rne_bf16(v[e] - fh);
        h[e]  = (short)hb;
        lo[e] = (short)lb;
    }
    Xfh[gid] = h;
    Xfl[gid] = lo;
}

// ---------------------------------------------------------------------------
// stage fp32 W regs -> split bf16 hi/lo in swizzled LDS (verified R2)
__device__ __forceinline__ void stage_store(char* Wh, char* Wl, const f32x4* wr,
                                            int wbyte0, int swz, int kq) {
#pragma unroll
    for (int i = 0; i < 4; ++i) {
        unsigned hb[4], lb[4];
#pragma unroll
        for (int e = 0; e < 4; ++e) {
            float f = wr[i][e];
            unsigned h = rne_bf16(f);
            float fh = __uint_as_float(h << 16);
            unsigned l = rne_bf16(f - fh);
            hb[e] = h; lb[e] = l;
        }
        short4v vh = { (short)hb[0], (short)hb[1], (short)hb[2], (short)hb[3] };
        short4v vl = { (short)lb[0], (short)lb[1], (short)lb[2], (short)lb[3] };
        const int kb   = (kq << 5) + (i << 3);     // byte offset of k within 256B row
        const int byte = wbyte0 + (kb ^ swz);
        *(short4v*)(Wh + byte) = vh;
        *(short4v*)(Wl + byte) = vl;
    }
}

// ---------------------------------------------------------------------------
// block-diagonal GEMM via bf16x3 MFMA emulation — R7 structure unchanged.
__global__ __launch_bounds__(256) void dend_gemm(const short8* __restrict__ Xfh,
                                                 const short8* __restrict__ Xfl,
                                                 const float*  __restrict__ W,
                                                 float* __restrict__ Yp) {
    __shared__ __align__(16) char WhL[2][32 * 256];
    __shared__ __align__(16) char WlL[2][32 * 256];
    __shared__ float Ys[32][65];

    const int t    = threadIdx.x;
    const int bid  = blockIdx.x;
    const int j    = bid & 3;
    const int o0   = ((bid >> 2) & 63) << 5;
    const int ks   = bid >> 8;         // K-segment 0..1
    const int lane = t & 63;
    const int wv   = t >> 6;           // wave = n-strip 0..3

    const int ri  = t >> 3;            // 0..31 (local o)
    const int kq  = t & 7;
    const float* wsrc = W + (size_t)((o0 + ri) * 4 + j) * IN_DIM
                          + j * CHUNK + ks * KSEG + kq * 16;
    const int wbyte0 = ri << 8;
    const int swz    = (ri & 15) << 4;

    const short8* pAh = Xfh + (j * 4 + wv) * 4096 + ks * 2048 + lane;
    const short8* pAl = Xfl + (j * 4 + wv) * 4096 + ks * 2048 + lane;

    const int o_l   = lane & 15;
    const int bswz  = o_l << 4;
    const int kgrp  = (lane >> 4) << 4;
    const int b0row = o_l << 8;
    const int b1row = (o_l + 16) << 8;

    f32x4 acc0 = {0.f, 0.f, 0.f, 0.f};
    f32x4 acc1 = {0.f, 0.f, 0.f, 0.f};

    f32x4  wr[4];
    short8 Ah0[4], Al0[4], Ah1[4], Al1[4];

    // ---- prologue ----
#pragma unroll
    for (int i = 0; i < 4; ++i)
        wr[i] = *(const f32x4*)(wsrc + i * 4);
    stage_store(WhL[0], WlL[0], wr, wbyte0, swz, kq);
#pragma unroll
    for (int i = 0; i < 4; ++i)
        wr[i] = *(const f32x4*)(wsrc + KT + i * 4);
#pragma unroll
    for (int i = 0; i < 4; ++i) { Ah0[i] = pAh[i * 64];       Al0[i] = pAl[i * 64]; }
#pragma unroll
    for (int i = 0; i < 4; ++i) { Ah1[i] = pAh[(4 + i) * 64]; Al1[i] = pAl[(4 + i) * 64]; }
    LBAR();

#define BODY(kt, AH, AL)                                                            \
  {                                                                                 \
    if ((kt) + 1 < NT)                                                              \
        stage_store(WhL[((kt) + 1) & 1], WlL[((kt) + 1) & 1], wr, wbyte0, swz, kq); \
    if ((kt) + 2 < NT) {                                                            \
        _Pragma("unroll")                                                           \
        for (int i = 0; i < 4; ++i)                                                 \
            wr[i] = *(const f32x4*)(wsrc + ((kt) + 2) * KT + i * 4);                \
    }                                                                               \
    _Pragma("unroll")                                                               \
    for (int st = 0; st < 4; ++st) {                                                \
        const int off = ((st << 6) + kgrp) ^ bswz;                                  \
        short8 bh0 = *(const short8*)(&WhL[(kt) & 1][b0row + off]);                 \
        short8 bl0 = *(const short8*)(&WlL[(kt) & 1][b0row + off]);                 \
        short8 bh1 = *(const short8*)(&WhL[(kt) & 1][b1row + off]);                 \
        short8 bl1 = *(const short8*)(&WlL[(kt) & 1][b1row + off]);                 \
        acc0 = __builtin_amdgcn_mfma_f32_16x16x32_bf16(AH[st], bh0, acc0, 0, 0, 0); \
        acc1 = __builtin_amdgcn_mfma_f32_16x16x32_bf16(AH[st], bh1, acc1, 0, 0, 0); \
        acc0 = __builtin_amdgcn_mfma_f32_16x16x32_bf16(AL[st], bh0, acc0, 0, 0, 0); \
        acc1 = __builtin_amdgcn_mfma_f32_16x16x32_bf16(AL[st], bh1, acc1, 0, 0, 0); \
        acc0 = __builtin_amdgcn_mfma_f32_16x16x32_bf16(AH[st], bl0, acc0, 0, 0, 0); \
        acc1 = __builtin_amdgcn_mfma_f32_16x16x32_bf16(AH[st], bl1, acc1, 0, 0, 0); \
    }                                                                               \
    if ((kt) + 2 < NT) {                                                            \
        _Pragma("unroll")                                                           \
        for (int i = 0; i < 4; ++i) {                                               \
            AH[i] = pAh[(((kt) + 2) * 4 + i) * 64];                                 \
            AL[i] = pAl[(((kt) + 2) * 4 + i) * 64];                                 \
        }                                                                           \
    }                                                                               \
    LBAR();                                                                         \
  }

#pragma unroll 1
    for (int kt = 0; kt < NT; kt += 2) {
        BODY(kt,     Ah0, Al0)
        BODY(kt + 1, Ah1, Al1)
    }
#undef BODY

    // ---- epilogue ----
    {
        const int rb = (wv << 4) + ((lane >> 4) << 2);
#pragma unroll
        for (int r = 0; r < 4; ++r) {
            Ys[o_l][rb + r]      = acc0[r];
            Ys[o_l + 16][rb + r] = acc1[r];
        }
    }
    __syncthreads();
#pragma unroll
    for (int p = 0; p < 8; ++p) {
        const int e  = t + (p << 8);
        const int oo = e & 31;
        const int n  = e >> 5;
        Yp[(size_t)(((ks * BATCH + n) << 2) + j) * OUT_DIM + o0 + oo] = Ys[oo][n];
    }
}

// ---------------------------------------------------------------------------
// pointwise dendritic decay + LIF + spike; sums the K-segment partials
__global__ __launch_bounds__(256) void lif_pointwise(
    const float* __restrict__ Yp,
    const float* __restrict__ mem,
    const float* __restrict__ spike,
    const float* __restrict__ d_input,
    const float* __restrict__ v_th,
    const float* __restrict__ b,
    const float* __restrict__ tau_m,
    const float* __restrict__ tau_n,
    float* __restrict__ out)
{
    const int idx = blockIdx.x * 256 + threadIdx.x;   // = n*OUT_DIM + o
    const int o   = idx & (OUT_DIM - 1);
    const int n   = idx >> 11;

    const float4 tn = ((const float4*)tau_n)[o];
    const float4 bb = ((const float4*)b)[o];
    const float4 di = ((const float4*)d_input)[idx];

    float y0 = 0.f, y1 = 0.f, y2 = 0.f, y3 = 0.f;
#pragma unroll
    for (int s = 0; s < NSEG; ++s) {
        const size_t base = (size_t)((s * BATCH + n) << 2) * OUT_DIM + o;
        y0 += Yp[base];
        y1 += Yp[base + OUT_DIM];
        y2 += Yp[base + 2 * OUT_DIM];
        y3 += Yp[base + 3 * OUT_DIM];
    }

    float l = 0.0f;
    { const float bt = sigmoidf_(tn.x); l += bt * di.x + (1.0f - bt) * (y0 + bb.x); }
    { const float bt = sigmoidf_(tn.y); l += bt * di.y + (1.0f - bt) * (y1 + bb.y); }
    { const float bt = sigmoidf_(tn.z); l += bt * di.z + (1.0f - bt) * (y2 + bb.z); }
    { const float bt = sigmoidf_(tn.w); l += bt * di.w + (1.0f - bt) * (y3 + bb.w); }

    const float alpha = sigmoidf_(tau_m[o]);
    const float vt    = v_th[idx];
    const float m     = mem[idx] * alpha + (1.0f - alpha) * l - vt * spike[idx];

    out[idx] = m;
    out[BATCH * OUT_DIM + idx] = (m - vt) > 0.0f ? 1.0f : 0.0f;
}

extern "C" void kernel_launch(void* const* d_in, const int* in_sizes, int n_in,
                              void* d_out, int out_size, void* d_ws, size_t ws_size,
                              hipStream_t stream) {
    const float* X     = (const float*)d_in[0];
    const float* mem   = (const float*)d_in[1];
    const float* spike = (const float*)d_in[2];
    const float* dinp  = (const float*)d_in[3];
    const float* vth   = (const float*)d_in[4];
    const float* W     = (const float*)d_in[5];
    const float* b     = (const float*)d_in[6];
    const float* tm    = (const float*)d_in[7];
    const float* tn    = (const float*)d_in[8];
    float* out = (float*)d_out;

    // workspace layout: Xfh (1 MB) | Xfl (1 MB) | Yp (4 MB: [seg][n][j][o])
    short8* Xfh = (short8*)d_ws;
    short8* Xfl = (short8*)((char*)d_ws + (1u << 20));
    float*  Yp  = (float*)((char*)d_ws + (2u << 20));

    // MEASUREMENT ROUND (vs R7 = 28.0 us):
    //   prep x2 (idempotent) and lif x2 (first reads stale Yp, overwritten by
    //   the real one). Delta = prep + lif + 2 launch gaps. Deterministic:
    //   identical sequence every call; final lif writes every out element.
    prep_x<<<256, 256, 0, stream>>>(X, Xfh, Xfl);
    prep_x<<<256, 256, 0, stream>>>(X, Xfh, Xfl);
    lif_pointwise<<<512, 256, 0, stream>>>(Yp, mem, spike, dinp, vth, b, tm, tn, out);
    dend_gemm<<<512, 256, 0, stream>>>(Xfh, Xfl, W, Yp);
    lif_pointwise<<<512, 256, 0, stream>>>(Yp, mem, spike, dinp, vth, b, tm, tn, out);
}

// Round 14
// 27.415 us; speedup vs baseline: 2.3241x; 1.1905x over previous
//
#include <hip/hip_runtime.h>
#include <math.h>

#define BATCH   64
#define IN_DIM  8192
#define OUT_DIM 2048
#define BRANCH  4
#define CHUNK   2048
#define NSEG    2      // K-split across blocks
#define KSEG    1024   // CHUNK / NSEG
#define KT      128    // k per LDS tile
#define NT      8      // KSEG / KT

typedef __attribute__((ext_vector_type(8))) short short8;   // 8 x bf16 (4 VGPR) MFMA operand
typedef __attribute__((ext_vector_type(4))) short short4v;  // 8-byte packed bf16x4
typedef __attribute__((ext_vector_type(4))) float f32x4;

__device__ __forceinline__ float sigmoidf_(float x) {
    return 1.0f / (1.0f + expf(-x));
}

// round-to-nearest-even fp32 -> bf16 bit pattern (low 16 bits of result)
__device__ __forceinline__ unsigned rne_bf16(float f) {
    unsigned u = __float_as_uint(f);
    return (u + 0x7fffu + ((u >> 16) & 1u)) >> 16;
}

// Barrier that does NOT drain vmcnt: LDS-visibility only (R7-verified safe).
#define LBAR()                                                   \
    do {                                                         \
        asm volatile("s_waitcnt lgkmcnt(0)" ::: "memory");       \
        __builtin_amdgcn_s_barrier();                            \
        asm volatile("" ::: "memory");                           \
    } while (0)

// ---------------------------------------------------------------------------
// prep: X fp32 [64][8192] -> A-fragment-layout bf16 hi/lo streams (RNE split —
// off the critical path, keep max precision).
__global__ __launch_bounds__(256) void prep_x(const float* __restrict__ X,
                                              short8* __restrict__ Xfh,
                                              short8* __restrict__ Xfl) {
    const int gid = blockIdx.x * 256 + threadIdx.x;   // 65536 frag-lanes
    const int l  = gid & 63;
    const int kk = (gid >> 6) & 63;
    const int s  = (gid >> 12) & 3;
    const int j  = gid >> 14;
    const int n  = s * 16 + (l & 15);
    const int k0 = kk * 32 + ((l >> 4) << 3);
    const float* p = X + (size_t)n * IN_DIM + j * CHUNK + k0;
    const f32x4 a = *(const f32x4*)p;
    const f32x4 c = *(const f32x4*)(p + 4);
    float v[8] = {a[0], a[1], a[2], a[3], c[0], c[1], c[2], c[3]};
    short8 h, lo;
#pragma unroll
    for (int e = 0; e < 8; ++e) {
        unsigned hb = rne_bf16(v[e]);
        float fh = __uint_as_float(hb << 16);
        unsigned lb = rne_bf16(v[e] - fh);
        h[e]  = (short)hb;
        lo[e] = (short)lb;
    }
    Xfh[gid] = h;
    Xfl[gid] = lo;
}

// ---------------------------------------------------------------------------
// stage fp32 W regs -> TRUNCATION-split bf16 hi/lo in swizzled LDS.
// hi = top 16 bits; lo = bf16_trunc(f - hi) (exact residual, Sterbenz).
// ~4 VALU/value vs ~10 for RNE — the R14 variable under test.
__device__ __forceinline__ void stage_store(char* Wh, char* Wl, const f32x4* wr,
                                            int wbyte0, int swz, int kq) {
#pragma unroll
    for (int i = 0; i < 4; ++i) {
        unsigned hb[4], lb[4];
#pragma unroll
        for (int e = 0; e < 4; ++e) {
            const float f  = wr[i][e];
            const unsigned u  = __float_as_uint(f);
            const float fl = f - __uint_as_float(u & 0xffff0000u);
            hb[e] = u >> 16;
            lb[e] = __float_as_uint(fl) >> 16;
        }
        short4v vh = { (short)hb[0], (short)hb[1], (short)hb[2], (short)hb[3] };
        short4v vl = { (short)lb[0], (short)lb[1], (short)lb[2], (short)lb[3] };
        const int kb   = (kq << 5) + (i << 3);     // byte offset of k within 256B row
        const int byte = wbyte0 + (kb ^ swz);
        *(short4v*)(Wh + byte) = vh;
        *(short4v*)(Wl + byte) = vl;
    }
}

// ---------------------------------------------------------------------------
// block-diagonal GEMM via bf16x3 MFMA emulation — R7 structure; trunc-split
// staging; Ys aliased onto dead W LDS (32 KB total).
__global__ __launch_bounds__(256) void dend_gemm(const short8* __restrict__ Xfh,
                                                 const short8* __restrict__ Xfl,
                                                 const float*  __restrict__ W,
                                                 float* __restrict__ Yp) {
    __shared__ __align__(16) char WhL[2][32 * 256];
    __shared__ __align__(16) char WlL[2][32 * 256];

    const int t    = threadIdx.x;
    const int bid  = blockIdx.x;
    const int j    = bid & 3;
    const int o0   = ((bid >> 2) & 63) << 5;
    const int ks   = bid >> 8;         // K-segment 0..1
    const int lane = t & 63;
    const int wv   = t >> 6;           // wave = n-strip 0..3

    const int ri  = t >> 3;            // 0..31 (local o)
    const int kq  = t & 7;
    const float* wsrc = W + (size_t)((o0 + ri) * 4 + j) * IN_DIM
                          + j * CHUNK + ks * KSEG + kq * 16;
    const int wbyte0 = ri << 8;
    const int swz    = (ri & 15) << 4;

    const short8* pAh = Xfh + (j * 4 + wv) * 4096 + ks * 2048 + lane;
    const short8* pAl = Xfl + (j * 4 + wv) * 4096 + ks * 2048 + lane;

    const int o_l   = lane & 15;
    const int bswz  = o_l << 4;
    const int kgrp  = (lane >> 4) << 4;
    const int b0row = o_l << 8;
    const int b1row = (o_l + 16) << 8;

    f32x4 acc0 = {0.f, 0.f, 0.f, 0.f};
    f32x4 acc1 = {0.f, 0.f, 0.f, 0.f};

    f32x4  wr[4];
    short8 Ah0[4], Al0[4], Ah1[4], Al1[4];

    // ---- prologue ----
#pragma unroll
    for (int i = 0; i < 4; ++i)
        wr[i] = *(const f32x4*)(wsrc + i * 4);
    stage_store(WhL[0], WlL[0], wr, wbyte0, swz, kq);
#pragma unroll
    for (int i = 0; i < 4; ++i)
        wr[i] = *(const f32x4*)(wsrc + KT + i * 4);
#pragma unroll
    for (int i = 0; i < 4; ++i) { Ah0[i] = pAh[i * 64];       Al0[i] = pAl[i * 64]; }
#pragma unroll
    for (int i = 0; i < 4; ++i) { Ah1[i] = pAh[(4 + i) * 64]; Al1[i] = pAl[(4 + i) * 64]; }
    LBAR();

#define BODY(kt, AH, AL)                                                            \
  {                                                                                 \
    if ((kt) + 1 < NT)                                                              \
        stage_store(WhL[((kt) + 1) & 1], WlL[((kt) + 1) & 1], wr, wbyte0, swz, kq); \
    if ((kt) + 2 < NT) {                                                            \
        _Pragma("unroll")                                                           \
        for (int i = 0; i < 4; ++i)                                                 \
            wr[i] = *(const f32x4*)(wsrc + ((kt) + 2) * KT + i * 4);                \
    }                                                                               \
    _Pragma("unroll")                                                               \
    for (int st = 0; st < 4; ++st) {                                                \
        const int off = ((st << 6) + kgrp) ^ bswz;                                  \
        short8 bh0 = *(const short8*)(&WhL[(kt) & 1][b0row + off]);                 \
        short8 bl0 = *(const short8*)(&WlL[(kt) & 1][b0row + off]);                 \
        short8 bh1 = *(const short8*)(&WhL[(kt) & 1][b1row + off]);                 \
        short8 bl1 = *(const short8*)(&WlL[(kt) & 1][b1row + off]);                 \
        acc0 = __builtin_amdgcn_mfma_f32_16x16x32_bf16(AH[st], bh0, acc0, 0, 0, 0); \
        acc1 = __builtin_amdgcn_mfma_f32_16x16x32_bf16(AH[st], bh1, acc1, 0, 0, 0); \
        acc0 = __builtin_amdgcn_mfma_f32_16x16x32_bf16(AL[st], bh0, acc0, 0, 0, 0); \
        acc1 = __builtin_amdgcn_mfma_f32_16x16x32_bf16(AL[st], bh1, acc1, 0, 0, 0); \
        acc0 = __builtin_amdgcn_mfma_f32_16x16x32_bf16(AH[st], bl0, acc0, 0, 0, 0); \
        acc1 = __builtin_amdgcn_mfma_f32_16x16x32_bf16(AH[st], bl1, acc1, 0, 0, 0); \
    }                                                                               \
    if ((kt) + 2 < NT) {                                                            \
        _Pragma("unroll")                                                           \
        for (int i = 0; i < 4; ++i) {                                               \
            AH[i] = pAh[(((kt) + 2) * 4 + i) * 64];                                 \
            AL[i] = pAl[(((kt) + 2) * 4 + i) * 64];                                 \
        }                                                                           \
    }                                                                               \
    LBAR();                                                                         \
  }

#pragma unroll 1
    for (int kt = 0; kt < NT; kt += 2) {
        BODY(kt,     Ah0, Al0)
        BODY(kt + 1, Ah1, Al1)
    }
#undef BODY

    // ---- epilogue: Ys aliased onto dead W buffers (all LDS reads drained by
    // the final LBAR's lgkmcnt(0)+barrier) ----
    float (*Ys)[65] = (float (*)[65])(&WhL[0][0]);   // 32 x 65 x 4B = 8.3 KB
    {
        const int rb = (wv << 4) + ((lane >> 4) << 2);
#pragma unroll
        for (int r = 0; r < 4; ++r) {
            Ys[o_l][rb + r]      = acc0[r];
            Ys[o_l + 16][rb + r] = acc1[r];
        }
    }
    __syncthreads();
#pragma unroll
    for (int p = 0; p < 8; ++p) {
        const int e  = t + (p << 8);
        const int oo = e & 31;
        const int n  = e >> 5;
        Yp[(size_t)(((ks * BATCH + n) << 2) + j) * OUT_DIM + o0 + oo] = Ys[oo][n];
    }
}

// ---------------------------------------------------------------------------
// pointwise dendritic decay + LIF + spike; sums the K-segment partials
__global__ __launch_bounds__(256) void lif_pointwise(
    const float* __restrict__ Yp,
    const float* __restrict__ mem,
    const float* __restrict__ spike,
    const float* __restrict__ d_input,
    const float* __restrict__ v_th,
    const float* __restrict__ b,
    const float* __restrict__ tau_m,
    const float* __restrict__ tau_n,
    float* __restrict__ out)
{
    const int idx = blockIdx.x * 256 + threadIdx.x;   // = n*OUT_DIM + o
    const int o   = idx & (OUT_DIM - 1);
    const int n   = idx >> 11;

    const float4 tn = ((const float4*)tau_n)[o];
    const float4 bb = ((const float4*)b)[o];
    const float4 di = ((const float4*)d_input)[idx];

    float y0 = 0.f, y1 = 0.f, y2 = 0.f, y3 = 0.f;
#pragma unroll
    for (int s = 0; s < NSEG; ++s) {
        const size_t base = (size_t)((s * BATCH + n) << 2) * OUT_DIM + o;
        y0 += Yp[base];
        y1 += Yp[base + OUT_DIM];
        y2 += Yp[base + 2 * OUT_DIM];
        y3 += Yp[base + 3 * OUT_DIM];
    }

    float l = 0.0f;
    { const float bt = sigmoidf_(tn.x); l += bt * di.x + (1.0f - bt) * (y0 + bb.x); }
    { const float bt = sigmoidf_(tn.y); l += bt * di.y + (1.0f - bt) * (y1 + bb.y); }
    { const float bt = sigmoidf_(tn.z); l += bt * di.z + (1.0f - bt) * (y2 + bb.z); }
    { const float bt = sigmoidf_(tn.w); l += bt * di.w + (1.0f - bt) * (y3 + bb.w); }

    const float alpha = sigmoidf_(tau_m[o]);
    const float vt    = v_th[idx];
    const float m     = mem[idx] * alpha + (1.0f - alpha) * l - vt * spike[idx];

    out[idx] = m;
    out[BATCH * OUT_DIM + idx] = (m - vt) > 0.0f ? 1.0f : 0.0f;
}

extern "C" void kernel_launch(void* const* d_in, const int* in_sizes, int n_in,
                              void* d_out, int out_size, void* d_ws, size_t ws_size,
                              hipStream_t stream) {
    const float* X     = (const float*)d_in[0];
    const float* mem   = (const float*)d_in[1];
    const float* spike = (const float*)d_in[2];
    const float* dinp  = (const float*)d_in[3];
    const float* vth   = (const float*)d_in[4];
    const float* W     = (const float*)d_in[5];
    const float* b     = (const float*)d_in[6];
    const float* tm    = (const float*)d_in[7];
    const float* tn    = (const float*)d_in[8];
    float* out = (float*)d_out;

    // workspace layout: Xfh (1 MB) | Xfl (1 MB) | Yp (4 MB: [seg][n][j][o])
    short8* Xfh = (short8*)d_ws;
    short8* Xfl = (short8*)((char*)d_ws + (1u << 20));
    float*  Yp  = (float*)((char*)d_ws + (2u << 20));

    prep_x<<<256, 256, 0, stream>>>(X, Xfh, Xfl);
    dend_gemm<<<512, 256, 0, stream>>>(Xfh, Xfl, W, Yp);
    lif_pointwise<<<512, 256, 0, stream>>>(Yp, mem, spike, dinp, vth, b, tm, tn, out);
}